// Round 17
// baseline (274.794 us; speedup 1.0000x reference)
//
#include <hip/hip_runtime.h>

#define N_NODES 50000
#define BN_EPS 1e-5f
#define GEMMBLK 391
#define GEMMBLK1S 782
#define FILLBLK 512
#define PREPBLK 24
#define EWINITBLK 200
#define ZROW N_NODES

typedef __attribute__((ext_vector_type(8))) short short8;
typedef __attribute__((ext_vector_type(4))) float f32x4;

__device__ __forceinline__ unsigned short f2b(float x) {
    unsigned int u = __float_as_uint(x);
    unsigned int r = (u + 0x7fffu + ((u >> 16) & 1u)) >> 16;
    return (unsigned short)r;
}
__device__ __forceinline__ float b2f_lo(unsigned int u) { return __uint_as_float(u << 16); }
__device__ __forceinline__ float b2f_hi(unsigned int u) { return __uint_as_float(u & 0xffff0000u); }
__device__ __forceinline__ unsigned int pack2(float lo, float hi) {
    return (unsigned int)f2b(lo) | ((unsigned int)f2b(hi) << 16);
}
__device__ __forceinline__ float us2f(unsigned short s) {
    return __uint_as_float(((unsigned int)s) << 16);
}

// per-block int64 detection: odd 32-bit words of first 256 edge entries all zero <=> int64
__device__ __forceinline__ int detect_is64(const int* __restrict__ e, int tid) {
    __shared__ int snz[4];
    int lane = tid & 63, wv = tid >> 6;
    int v = e[2 * tid + 1];
    unsigned long long b = __ballot(v != 0);
    if (lane == 0) snz[wv] = (b != 0ULL) ? 1 : 0;
    __syncthreads();
    return !(snz[0] | snz[1] | snz[2] | snz[3]);
}

__device__ __forceinline__ int edge_at(const int* e32, const long long* e64, int is64, long long idx) {
    return is64 ? (int)e64[idx] : e32[idx];
}

// ---------------- init: W prepack + ew <- ZROW pattern + zb zero row ----------------
__global__ void k_init(const float* __restrict__ W1, const float* __restrict__ W2,
                       const float* __restrict__ W3, const float* __restrict__ Wl,
                       unsigned short* __restrict__ bp, uint4* __restrict__ ew4,
                       unsigned int* __restrict__ zb32, int n) {
    if (blockIdx.x < PREPBLK) {
        int job = blockIdx.x >> 2, q = blockIdx.x & 3;
        const float* src;
        int rowoff = 0;
        if (job == 0) src = W1;
        else if (job == 1) src = W2;
        else if (job == 2) src = W3;
        else { src = Wl; rowoff = (job - 3) * 128; }
        unsigned short* dst = bp + job * 16384;
        for (int idx = q * 4096 + threadIdx.x; idx < q * 4096 + 4096; idx += 256) {
            int j = idx & 7, l = (idx >> 3) & 63, kt = (idx >> 9) & 3, nt = idx >> 11;
            int row = kt * 32 + (l >> 4) * 8 + j;
            int col = nt * 16 + (l & 15);
            dst[idx] = f2b(src[(rowoff + row) * 128 + col]);
        }
        return;
    }
    if (blockIdx.x == PREPBLK && threadIdx.x < 64)
        zb32[(size_t)n * 64 + threadIdx.x] = 0;   // ZROW zero row (128 bf16)
    // ew init: n*64 u16 = n*8 uint4, pattern ZROW in every u16
    unsigned int zz = ((unsigned int)ZROW << 16) | (unsigned int)ZROW;
    uint4 z = make_uint4(zz, zz, zz, zz);
    int total = n * 8;
    for (int i = (blockIdx.x - PREPBLK) * 256 + threadIdx.x; i < total; i += EWINITBLK * 256)
        ew4[i] = z;
}

// ---------------- shared GEMM body: zb = [dinv .*] (A @ Bp [+ c]), bf16 out ----------------
template <int HAS_C, int A32, int SCALE>
__device__ __forceinline__ void gemm_body(int bid, int nblocks, const void* __restrict__ Av,
                                          const unsigned short* __restrict__ Bp,
                                          const float* __restrict__ cvec,
                                          const float* __restrict__ dinv,
                                          unsigned short* __restrict__ zb, int n) {
    int tid = threadIdx.x;
    int l = tid & 63, w = tid >> 6;
    const short8* bp8 = (const short8*)Bp;
    short8 B[2][4];
#pragma unroll
    for (int i = 0; i < 2; ++i)
#pragma unroll
        for (int kt = 0; kt < 4; ++kt)
            B[i][kt] = bp8[((2 * w + i) * 4 + kt) * 64 + l];
    int kgrp = l >> 4, rit = l & 15, ccol = l & 15;
    int ntile = n >> 4;
    int col0 = 2 * w * 16 + ccol, col1 = col0 + 16;
    float cv0 = HAS_C ? cvec[col0] : 0.f;
    float cv1 = HAS_C ? cvec[col1] : 0.f;
    for (int t0 = bid * 4; t0 < ntile; t0 += nblocks * 4) {
        f32x4 acc[4][2];
#pragma unroll
        for (int tt = 0; tt < 4; ++tt) { acc[tt][0] = (f32x4)(0.f); acc[tt][1] = (f32x4)(0.f); }
#pragma unroll
        for (int kt = 0; kt < 4; ++kt) {
            short8 a[4];
#pragma unroll
            for (int tt = 0; tt < 4; ++tt) {
                int tile = min(t0 + tt, ntile - 1);
                size_t base = (size_t)(tile * 16 + rit) * 128 + kgrp * 8 + kt * 32;
                if (A32) {
                    const float* a32 = (const float*)Av + base;
                    float4 fa = *(const float4*)a32;
                    float4 fb = *(const float4*)(a32 + 4);
                    short8 af;
                    af[0] = (short)f2b(fa.x); af[1] = (short)f2b(fa.y);
                    af[2] = (short)f2b(fa.z); af[3] = (short)f2b(fa.w);
                    af[4] = (short)f2b(fb.x); af[5] = (short)f2b(fb.y);
                    af[6] = (short)f2b(fb.z); af[7] = (short)f2b(fb.w);
                    a[tt] = af;
                } else {
                    a[tt] = *(const short8*)((const unsigned short*)Av + base);
                }
            }
#pragma unroll
            for (int tt = 0; tt < 4; ++tt) {
                acc[tt][0] = __builtin_amdgcn_mfma_f32_16x16x32_bf16(a[tt], B[0][kt], acc[tt][0], 0, 0, 0);
                acc[tt][1] = __builtin_amdgcn_mfma_f32_16x16x32_bf16(a[tt], B[1][kt], acc[tt][1], 0, 0, 0);
            }
        }
        int crow0 = kgrp * 4;
#pragma unroll
        for (int tt = 0; tt < 4; ++tt) {
            int tile = t0 + tt;
            if (tile < ntile) {
                int r0 = tile * 16;
#pragma unroll
                for (int j = 0; j < 4; ++j) {
                    int row = r0 + crow0 + j;
                    float dv = SCALE ? dinv[row] : 1.f;
                    float v0 = acc[tt][0][j] + cv0;
                    float v1 = acc[tt][1][j] + cv1;
                    if (SCALE) { v0 *= dv; v1 *= dv; }
                    zb[(size_t)row * 128 + col0] = f2b(v0);
                    zb[(size_t)row * 128 + col1] = f2b(v1);
                }
            }
        }
    }
}

// ---------------- fill body: fixed-64-slot scatter, 8-deep pipelined atomics ----------------
__device__ __forceinline__ void fill_body(int bid, int nblocks, const int* __restrict__ e,
                                          int* __restrict__ cnt16,
                                          unsigned short* __restrict__ ew, int E) {
    int is64 = detect_is64(e, threadIdx.x);
    const long long* e64 = (const long long*)e;
    int T = nblocks * 256;
    for (int base = bid * 256 + threadIdx.x; base < E; base += T * 8) {
        int d[8], s[8], pos[8];
        bool vld[8];
#pragma unroll
        for (int j = 0; j < 8; ++j) {
            int idx = base + j * T;
            vld[j] = idx < E;
            int ci = vld[j] ? idx : 0;
            d[j] = edge_at(e, e64, is64, (long long)E + ci);
            s[j] = edge_at(e, e64, is64, ci);
        }
#pragma unroll
        for (int j = 0; j < 8; ++j)
            pos[j] = vld[j] ? atomicAdd(&cnt16[d[j] << 4], 1) : 64;
#pragma unroll
        for (int j = 0; j < 8; ++j)
            if (vld[j] && pos[j] < 63) ew[d[j] * 64 + pos[j]] = (unsigned short)s[j];
    }
}

// fused layer-1 GEMM (unscaled z) + edge fill (independent; fill hides under MFMA)
__global__ __launch_bounds__(256) void k_gemm1_fill(const float* __restrict__ x,
                                                    const unsigned short* __restrict__ Bp,
                                                    unsigned short* __restrict__ zb,
                                                    const int* __restrict__ e,
                                                    int* __restrict__ cnt16,
                                                    unsigned short* __restrict__ ew,
                                                    int E, int n) {
    if (blockIdx.x < GEMMBLK)
        gemm_body<0, 1, 0>(blockIdx.x, GEMMBLK, x, Bp, nullptr, nullptr, zb, n);
    else
        fill_body(blockIdx.x - GEMMBLK, FILLBLK, e, cnt16, ew, E);
}

// standalone layer GEMM (layers 2,3): dinv-scaled epilogue
template <int HAS_C, int A32>
__global__ __launch_bounds__(256) void k_gemm_z(const void* __restrict__ Av,
                                                const unsigned short* __restrict__ Bp,
                                                const float* __restrict__ cvec,
                                                const float* __restrict__ dinv,
                                                unsigned short* __restrict__ zb, int n) {
    gemm_body<HAS_C, A32, 1>(blockIdx.x, gridDim.x, Av, Bp, cvec, dinv, zb, n);
}

// ---------------- post-fill: dinv, self-loop slots, zb *= dinv (layer 1) ----------------
__global__ __launch_bounds__(256) void k_post(const int* __restrict__ cnt16,
                                              float* __restrict__ dinv,
                                              unsigned short* __restrict__ ew,
                                              unsigned int* __restrict__ zb32, int n) {
    __shared__ float sdv[256];
    int t = threadIdx.x;
    int node = blockIdx.x * 256 + t;
    float dv = 0.f;
    if (node < n) {
        int c = cnt16[node << 4];
        dv = rsqrtf((float)(c + 1));
        dinv[node] = dv;
        ew[node * 64 + min(c, 63)] = (unsigned short)node;   // self loop
    }
    sdv[t] = dv;
    __syncthreads();
    int base = blockIdx.x * 16384;   // 256 rows * 64 u32
    for (int i = t; i < 16384; i += 256) {
        int row_local = i >> 6;
        if (blockIdx.x * 256 + row_local < n) {
            unsigned int u = zb32[base + i];
            float dvv = sdv[row_local];
            zb32[base + i] = pack2(b2f_lo(u) * dvv, b2f_hi(u) * dvv);
        }
    }
}

// ---------------- aggregate + relu + BN stats: FOUR nodes per wave, interleaved ----------------
// Fixed 64-slot rows (8 uint4 per row), ZROW pads -> no guards: 32 gathers + 4 edge loads in flight.
__global__ __launch_bounds__(256) void k_agg(const unsigned short* __restrict__ zb,
                                             const int* __restrict__ cnt16,
                                             const unsigned short* __restrict__ ew,
                                             const float* __restrict__ dinv,
                                             const float* __restrict__ bias,
                                             unsigned int* __restrict__ tb,
                                             float* __restrict__ stats64, int n) {
    int tid = threadIdx.x;
    int l = tid & 63;
    int wid = __builtin_amdgcn_readfirstlane(blockIdx.x * 4 + (tid >> 6));
    int node0 = wid * 4;
    const unsigned int* zl = (const unsigned int*)zb + l;
    float s0[4] = {0.f, 0.f, 0.f, 0.f}, s1[4] = {0.f, 0.f, 0.f, 0.f};
    int iters = 0;
#pragma unroll
    for (int ni = 0; ni < 4; ++ni)
        iters = max(iters, (cnt16[(node0 + ni) << 4] + 8) >> 3);   // <= 8
    const uint4* ep0 = (const uint4*)(ew + (size_t)node0 * 64);    // 8 uint4 per node row
    uint4 q[4];
#pragma unroll
    for (int ni = 0; ni < 4; ++ni) q[ni] = ep0[ni * 8];
    for (int it = 1; it <= iters; ++it) {
        unsigned int u[4][8];
#pragma unroll
        for (int ni = 0; ni < 4; ++ni) {
            u[ni][0] = zl[(q[ni].x & 0xffffu) << 6];
            u[ni][1] = zl[(q[ni].x >> 16) << 6];
            u[ni][2] = zl[(q[ni].y & 0xffffu) << 6];
            u[ni][3] = zl[(q[ni].y >> 16) << 6];
            u[ni][4] = zl[(q[ni].z & 0xffffu) << 6];
            u[ni][5] = zl[(q[ni].z >> 16) << 6];
            u[ni][6] = zl[(q[ni].w & 0xffffu) << 6];
            u[ni][7] = zl[(q[ni].w >> 16) << 6];
        }
#pragma unroll
        for (int ni = 0; ni < 4; ++ni)
            q[ni] = ep0[ni * 8 + it];   // slack-safe prefetch (next-row reads unused at end)
#pragma unroll
        for (int ni = 0; ni < 4; ++ni) {
#pragma unroll
            for (int j = 0; j < 8; ++j) {
                s0[ni] += b2f_lo(u[ni][j]);
                s1[ni] += b2f_hi(u[ni][j]);
            }
        }
    }
    float b0f = bias[2 * l], b1f = bias[2 * l + 1];
    float r0 = 0.f, r1 = 0.f, r2 = 0.f, r3 = 0.f;
#pragma unroll
    for (int ni = 0; ni < 4; ++ni) {
        float dd = dinv[node0 + ni];
        float a0 = fmaxf(fmaf(s0[ni], dd, b0f), 0.f);
        float a1 = fmaxf(fmaf(s1[ni], dd, b1f), 0.f);
        tb[((size_t)(node0 + ni) << 6) | l] = pack2(a0, a1);
        r0 += a0; r1 += a1;
        r2 = fmaf(a0, a0, r2); r3 = fmaf(a1, a1, r3);
    }
    __shared__ float red[4][256];
    red[0][tid] = r0; red[1][tid] = r1; red[2][tid] = r2; red[3][tid] = r3;
    __syncthreads();
    int k = tid >> 6, li = tid & 63;
    float v = red[k][li] + red[k][64 + li] + red[k][128 + li] + red[k][192 + li];
    int f = 2 * li + (k & 1) + ((k >> 1) ? 128 : 0);
    atomicAdd(&stats64[(blockIdx.x & 63) * 256 + f], v);
}

// ---------------- fused BN finalize + shift-dots + B pre-scale ----------------
template <int MODE>
__global__ void k_bn_findots(const float* __restrict__ stats64,
                             const float* __restrict__ g, const float* __restrict__ be,
                             float invn, float* __restrict__ ss_out,
                             const float* __restrict__ Wn, float* __restrict__ cn,
                             const float* __restrict__ Wl, const float* __restrict__ base,
                             float* __restrict__ cl,
                             const unsigned short* __restrict__ bpn_src,
                             unsigned short* __restrict__ bpn_dst,
                             const unsigned short* __restrict__ bpl_src,
                             unsigned short* __restrict__ bpl_dst) {
    int tid = threadIdx.x;  // 256
    float a = 0.f;
#pragma unroll 8
    for (int c = 0; c < 64; ++c) a += stats64[c * 256 + tid];
    __shared__ float sums[256];
    __shared__ float sh[128];
    __shared__ float scs[128];
    sums[tid] = a;
    __syncthreads();
    if (tid < 128) {
        float m = sums[tid] * invn;
        float var = sums[128 + tid] * invn - m * m;
        float sc = g[tid] * rsqrtf(var + BN_EPS);
        scs[tid] = sc;
        sh[tid] = fmaf(-m, sc, be[tid]);
    }
    __syncthreads();
    if (blockIdx.x == 0 && tid < 128) {
        ss_out[tid] = scs[tid];
        ss_out[128 + tid] = sh[tid];
    }
    bool doCl = (MODE == 2) ? (blockIdx.x == 0) : (blockIdx.x == 1);
    bool doCn = (MODE < 2) && (blockIdx.x == 0);
    if (doCl || doCn) {
        const float* W = doCl ? Wl : Wn;
        int col = tid & 127, half = tid >> 7;
        float acc = 0.f;
#pragma unroll 4
        for (int k = half * 64; k < half * 64 + 64; ++k) acc = fmaf(sh[k], W[k * 128 + col], acc);
        __syncthreads();
        sums[tid] = acc;
        __syncthreads();
        if (tid < 128) {
            float tot = sums[tid] + sums[128 + tid];
            if (doCl) cl[tid] = ((MODE == 0) ? base[tid] : cl[tid]) + tot;
            else cn[tid] = tot;
        }
    }
    // scale prepacked B fragments by per-k scs
    int beg = blockIdx.x * 8192;
    if (MODE < 2) {
        for (int idx = beg + tid; idx < beg + 8192; idx += 256) {
            int k = ((idx >> 9) & 3) * 32 + ((idx >> 7) & 3) * 8 + (idx & 7);
            bpn_dst[idx] = f2b(us2f(bpn_src[idx]) * scs[k]);
        }
    }
    for (int idx = beg + tid; idx < beg + 8192; idx += 256) {
        int k = ((idx >> 9) & 3) * 32 + ((idx >> 7) & 3) * 8 + (idx & 7);
        bpl_dst[idx] = f2b(us2f(bpl_src[idx]) * scs[k]);
    }
}

// ---------------- final GEMM: out = relu([t1|t2|t3] @ BpL + cl), all-reg B ----------------
__global__ __launch_bounds__(256) void k_gemm_final(const unsigned short* __restrict__ t1,
                                                    const unsigned short* __restrict__ t2,
                                                    const unsigned short* __restrict__ t3,
                                                    const unsigned short* __restrict__ Bp,
                                                    const float* __restrict__ cl,
                                                    float* __restrict__ out, int n) {
    int tid = threadIdx.x;
    int l = tid & 63, w = tid >> 6;
    const short8* bp8 = (const short8*)Bp;
    short8 B[2][12];
#pragma unroll
    for (int b = 0; b < 3; ++b)
#pragma unroll
        for (int i = 0; i < 2; ++i)
#pragma unroll
            for (int kt = 0; kt < 4; ++kt)
                B[i][b * 4 + kt] = bp8[b * 2048 + ((2 * w + i) * 4 + kt) * 64 + l];
    int kgrp = l >> 4, rit = l & 15, ccol = l & 15;
    int ntile = n >> 4;
    int col0 = 2 * w * 16 + ccol, col1 = col0 + 16;
    float cv0 = cl[col0], cv1 = cl[col1];
    const unsigned short* tbs[3] = {t1, t2, t3};
    for (int t0 = blockIdx.x * 4; t0 < ntile; t0 += gridDim.x * 4) {
        f32x4 acc[4][2];
#pragma unroll
        for (int tt = 0; tt < 4; ++tt) { acc[tt][0] = (f32x4)(0.f); acc[tt][1] = (f32x4)(0.f); }
#pragma unroll
        for (int b = 0; b < 3; ++b) {
            const unsigned short* tp = tbs[b];
#pragma unroll
            for (int kt = 0; kt < 4; ++kt) {
                short8 a[4];
#pragma unroll
                for (int tt = 0; tt < 4; ++tt) {
                    int tile = min(t0 + tt, ntile - 1);
                    a[tt] = *(const short8*)(tp + (size_t)(tile * 16 + rit) * 128 + kgrp * 8 + kt * 32);
                }
#pragma unroll
                for (int tt = 0; tt < 4; ++tt) {
                    acc[tt][0] = __builtin_amdgcn_mfma_f32_16x16x32_bf16(a[tt], B[0][b * 4 + kt], acc[tt][0], 0, 0, 0);
                    acc[tt][1] = __builtin_amdgcn_mfma_f32_16x16x32_bf16(a[tt], B[1][b * 4 + kt], acc[tt][1], 0, 0, 0);
                }
            }
        }
        int crow0 = kgrp * 4;
#pragma unroll
        for (int tt = 0; tt < 4; ++tt) {
            int tile = t0 + tt;
            if (tile < ntile) {
                int r0 = tile * 16;
#pragma unroll
                for (int j = 0; j < 4; ++j) {
                    int row = r0 + crow0 + j;
                    out[(size_t)row * 128 + col0] = fmaxf(acc[tt][0][j] + cv0, 0.f);
                    out[(size_t)row * 128 + col1] = fmaxf(acc[tt][1][j] + cv1, 0.f);
                }
            }
        }
    }
}

extern "C" void kernel_launch(void* const* d_in, const int* in_sizes, int n_in,
                              void* d_out, int out_size, void* d_ws, size_t ws_size,
                              hipStream_t stream) {
    const float* x   = (const float*)d_in[0];
    const int*   ei  = (const int*)d_in[1];
    const float* W1  = (const float*)d_in[3];
    const float* b1  = (const float*)d_in[4];
    const float* g1  = (const float*)d_in[5];
    const float* be1 = (const float*)d_in[6];
    const float* W2  = (const float*)d_in[7];
    const float* b2  = (const float*)d_in[8];
    const float* g2  = (const float*)d_in[9];
    const float* be2 = (const float*)d_in[10];
    const float* W3  = (const float*)d_in[11];
    const float* b3  = (const float*)d_in[12];
    const float* g3  = (const float*)d_in[13];
    const float* be3 = (const float*)d_in[14];
    const float* Wl  = (const float*)d_in[15];
    const float* bl  = (const float*)d_in[16];
    float* out = (float*)d_out;

    const int n = N_NODES;
    const int E = in_sizes[1] / 2;

    char* ws = (char*)d_ws;
    size_t off = 0;
    auto alloc = [&](size_t bytes) -> void* {
        void* p = ws + off;
        off += (bytes + 255) & ~((size_t)255);
        return p;
    };
    // zero-region: strided cnt + 3 striped stats buffers, contiguous, one memset
    int*            cnt16    = (int*)alloc((size_t)n * 16 * 4);
    float*          st1      = (float*)alloc(64 * 256 * 4);
    float*          st2      = (float*)alloc(64 * 256 * 4);
    float*          st3      = (float*)alloc(64 * 256 * 4);
    size_t zero_bytes = (size_t)((char*)st3 + 64 * 256 * 4 - (char*)cnt16);

    float*          dinv     = (float*)alloc((size_t)n * 4);
    float*          ss1      = (float*)alloc(256 * 4);
    float*          ss2      = (float*)alloc(256 * 4);
    float*          ss3      = (float*)alloc(256 * 4);
    float*          c2       = (float*)alloc(128 * 4);
    float*          c3       = (float*)alloc(128 * 4);
    float*          cl       = (float*)alloc(128 * 4);
    unsigned short* ew       = (unsigned short*)alloc(((size_t)n * 64 + 1024) * 2);  // fixed 64 slots/node
    unsigned short* bp       = (unsigned short*)alloc(6 * 16384 * 2);   // raw prepack
    unsigned short* bpsN     = (unsigned short*)alloc(16384 * 2);       // scaled next-layer W
    unsigned short* bpsL     = (unsigned short*)alloc(3 * 16384 * 2);   // scaled Wl blocks
    unsigned short* zb       = (unsigned short*)alloc((size_t)(n + 1) * 128 * 2);  // +zero row
    unsigned int*   tb1      = (unsigned int*)alloc((size_t)n * 64 * 4);
    unsigned int*   tb2      = (unsigned int*)alloc((size_t)n * 64 * 4);
    unsigned int*   tb3      = (unsigned int*)alloc((size_t)n * 64 * 4);

    hipMemsetAsync(cnt16, 0, zero_bytes, stream);

    // ---- init: prepack + ew pattern-fill + zb zero row (no deg_count, no scan) ----
    k_init<<<PREPBLK + EWINITBLK, 256, 0, stream>>>(W1, W2, W3, Wl, bp, (uint4*)ew,
                                                    (unsigned int*)zb, n);

    const unsigned short* t1u = (const unsigned short*)tb1;
    const unsigned short* t2u = (const unsigned short*)tb2;
    const unsigned short* t3u = (const unsigned short*)tb3;
    float invn = 1.0f / n;
    int aggblk = n / 16;   // four nodes per wave

    // ---- layer 1 GEMM (unscaled) fused with edge fill ----
    k_gemm1_fill<<<GEMMBLK + FILLBLK, 256, 0, stream>>>(x, bp, zb, ei, cnt16, ew, E, n);
    // ---- post: dinv, self-loop slots, zb *= dinv ----
    k_post<<<(n + 255) / 256, 256, 0, stream>>>(cnt16, dinv, ew, (unsigned int*)zb, n);

    k_agg<<<aggblk, 256, 0, stream>>>(zb, cnt16, ew, dinv, b1, tb1, st1, n);
    k_bn_findots<0><<<2, 256, 0, stream>>>(st1, g1, be1, invn, ss1, W2, c2, Wl, bl, cl,
                                           bp + 16384, bpsN, bp + 3 * 16384, bpsL);

    // ---- layer 2 (prescaled W2) ----
    k_gemm_z<1, 0><<<GEMMBLK1S, 256, 0, stream>>>(t1u, bpsN, c2, dinv, zb, n);
    k_agg<<<aggblk, 256, 0, stream>>>(zb, cnt16, ew, dinv, b2, tb2, st2, n);
    k_bn_findots<1><<<2, 256, 0, stream>>>(st2, g2, be2, invn, ss2, W3, c3, Wl + 16384, nullptr, cl,
                                           bp + 2 * 16384, bpsN, bp + 4 * 16384, bpsL + 16384);

    // ---- layer 3 (prescaled W3) ----
    k_gemm_z<1, 0><<<GEMMBLK1S, 256, 0, stream>>>(t2u, bpsN, c3, dinv, zb, n);
    k_agg<<<aggblk, 256, 0, stream>>>(zb, cnt16, ew, dinv, b3, tb3, st3, n);
    k_bn_findots<2><<<2, 256, 0, stream>>>(st3, g3, be3, invn, ss3, nullptr, nullptr,
                                           Wl + 2 * 16384, nullptr, cl,
                                           nullptr, nullptr, bp + 5 * 16384, bpsL + 2 * 16384);

    // ---- final fused GEMM over K=384 (prescaled Wl, all-reg B) ----
    k_gemm_final<<<GEMMBLK1S, 256, 0, stream>>>(t1u, t2u, t3u, bpsL, cl, out, n);
}

// Round 18
// 270.720 us; speedup vs baseline: 1.0150x; 1.0150x over previous
//
#include <hip/hip_runtime.h>

#define N_NODES 50000
#define BN_EPS 1e-5f
#define GEMMBLK 391
#define FILLBLK 512
#define PREPBLK 24
#define EWINITBLK 200
#define ZROW N_NODES

typedef __attribute__((ext_vector_type(8))) short short8;
typedef __attribute__((ext_vector_type(4))) float f32x4;

__device__ __forceinline__ unsigned short f2b(float x) {
    unsigned int u = __float_as_uint(x);
    unsigned int r = (u + 0x7fffu + ((u >> 16) & 1u)) >> 16;
    return (unsigned short)r;
}
__device__ __forceinline__ float b2f_lo(unsigned int u) { return __uint_as_float(u << 16); }
__device__ __forceinline__ float b2f_hi(unsigned int u) { return __uint_as_float(u & 0xffff0000u); }
__device__ __forceinline__ unsigned int pack2(float lo, float hi) {
    return (unsigned int)f2b(lo) | ((unsigned int)f2b(hi) << 16);
}
__device__ __forceinline__ float us2f(unsigned short s) {
    return __uint_as_float(((unsigned int)s) << 16);
}

// per-block int64 detection: odd 32-bit words of first 256 edge entries all zero <=> int64
__device__ __forceinline__ int detect_is64(const int* __restrict__ e, int tid) {
    __shared__ int snz[4];
    int lane = tid & 63, wv = tid >> 6;
    int v = e[2 * tid + 1];
    unsigned long long b = __ballot(v != 0);
    if (lane == 0) snz[wv] = (b != 0ULL) ? 1 : 0;
    __syncthreads();
    return !(snz[0] | snz[1] | snz[2] | snz[3]);
}

__device__ __forceinline__ int edge_at(const int* e32, const long long* e64, int is64, long long idx) {
    return is64 ? (int)e64[idx] : e32[idx];
}

// ---------------- init: W prepack + ew <- ZROW pattern + zb zero row ----------------
__global__ void k_init(const float* __restrict__ W1, const float* __restrict__ W2,
                       const float* __restrict__ W3, const float* __restrict__ Wl,
                       unsigned short* __restrict__ bp, uint4* __restrict__ ew4,
                       unsigned int* __restrict__ zb32, int n) {
    if (blockIdx.x < PREPBLK) {
        int job = blockIdx.x >> 2, q = blockIdx.x & 3;
        const float* src;
        int rowoff = 0;
        if (job == 0) src = W1;
        else if (job == 1) src = W2;
        else if (job == 2) src = W3;
        else { src = Wl; rowoff = (job - 3) * 128; }
        unsigned short* dst = bp + job * 16384;
        for (int idx = q * 4096 + threadIdx.x; idx < q * 4096 + 4096; idx += 256) {
            int j = idx & 7, l = (idx >> 3) & 63, kt = (idx >> 9) & 3, nt = idx >> 11;
            int row = kt * 32 + (l >> 4) * 8 + j;
            int col = nt * 16 + (l & 15);
            dst[idx] = f2b(src[(rowoff + row) * 128 + col]);
        }
        return;
    }
    if (blockIdx.x == PREPBLK && threadIdx.x < 64)
        zb32[(size_t)n * 64 + threadIdx.x] = 0;   // ZROW zero row (128 bf16)
    // ew init: n*64 u16 = n*8 uint4, pattern ZROW in every u16
    unsigned int zz = ((unsigned int)ZROW << 16) | (unsigned int)ZROW;
    uint4 z = make_uint4(zz, zz, zz, zz);
    int total = n * 8;
    for (int i = (blockIdx.x - PREPBLK) * 256 + threadIdx.x; i < total; i += EWINITBLK * 256)
        ew4[i] = z;
}

// ---------------- fill: fixed-64-slot scatter, 8-deep pipelined atomics ----------------
__global__ __launch_bounds__(256) void k_fill(const int* __restrict__ e,
                                              int* __restrict__ cnt16,
                                              unsigned short* __restrict__ ew, int E) {
    int is64 = detect_is64(e, threadIdx.x);
    const long long* e64 = (const long long*)e;
    int T = FILLBLK * 256;
    for (int base = blockIdx.x * 256 + threadIdx.x; base < E; base += T * 8) {
        int d[8], s[8], pos[8];
        bool vld[8];
#pragma unroll
        for (int j = 0; j < 8; ++j) {
            int idx = base + j * T;
            vld[j] = idx < E;
            int ci = vld[j] ? idx : 0;
            d[j] = edge_at(e, e64, is64, (long long)E + ci);
            s[j] = edge_at(e, e64, is64, ci);
        }
#pragma unroll
        for (int j = 0; j < 8; ++j)
            pos[j] = vld[j] ? atomicAdd(&cnt16[d[j] << 4], 1) : 64;
#pragma unroll
        for (int j = 0; j < 8; ++j)
            if (vld[j] && pos[j] < 63) ew[d[j] * 64 + pos[j]] = (unsigned short)s[j];
    }
}

// ---------------- dinv + self-loop slot (tiny) ----------------
__global__ void k_dinv_self(const int* __restrict__ cnt16, float* __restrict__ dinv,
                            unsigned short* __restrict__ ew, int n) {
    int node = blockIdx.x * 256 + threadIdx.x;
    if (node >= n) return;
    int c = cnt16[node << 4];
    dinv[node] = rsqrtf((float)(c + 1));
    ew[node * 64 + min(c, 63)] = (unsigned short)node;
}

// ---------------- layer GEMM: zb = dinv .* (A @ Bp [+ c]), bf16 out, persistent ----------------
template <int HAS_C, int A32>
__global__ __launch_bounds__(256) void k_gemm_z(const void* __restrict__ Av,
                                                const unsigned short* __restrict__ Bp,
                                                const float* __restrict__ cvec,
                                                const float* __restrict__ dinv,
                                                unsigned short* __restrict__ zb, int n) {
    int tid = threadIdx.x;
    int l = tid & 63, w = tid >> 6;
    const short8* bp8 = (const short8*)Bp;
    short8 B[2][4];
#pragma unroll
    for (int i = 0; i < 2; ++i)
#pragma unroll
        for (int kt = 0; kt < 4; ++kt)
            B[i][kt] = bp8[((2 * w + i) * 4 + kt) * 64 + l];
    int kgrp = l >> 4, rit = l & 15, ccol = l & 15;
    int ntile = n >> 4;
    int col0 = 2 * w * 16 + ccol, col1 = col0 + 16;
    float cv0 = HAS_C ? cvec[col0] : 0.f;
    float cv1 = HAS_C ? cvec[col1] : 0.f;
    for (int t0 = blockIdx.x * 4; t0 < ntile; t0 += gridDim.x * 4) {
        f32x4 acc[4][2];
#pragma unroll
        for (int tt = 0; tt < 4; ++tt) { acc[tt][0] = (f32x4)(0.f); acc[tt][1] = (f32x4)(0.f); }
#pragma unroll
        for (int kt = 0; kt < 4; ++kt) {
            short8 a[4];
#pragma unroll
            for (int tt = 0; tt < 4; ++tt) {
                int tile = min(t0 + tt, ntile - 1);
                size_t base = (size_t)(tile * 16 + rit) * 128 + kgrp * 8 + kt * 32;
                if (A32) {
                    const float* a32 = (const float*)Av + base;
                    float4 fa = *(const float4*)a32;
                    float4 fb = *(const float4*)(a32 + 4);
                    short8 af;
                    af[0] = (short)f2b(fa.x); af[1] = (short)f2b(fa.y);
                    af[2] = (short)f2b(fa.z); af[3] = (short)f2b(fa.w);
                    af[4] = (short)f2b(fb.x); af[5] = (short)f2b(fb.y);
                    af[6] = (short)f2b(fb.z); af[7] = (short)f2b(fb.w);
                    a[tt] = af;
                } else {
                    a[tt] = *(const short8*)((const unsigned short*)Av + base);
                }
            }
#pragma unroll
            for (int tt = 0; tt < 4; ++tt) {
                acc[tt][0] = __builtin_amdgcn_mfma_f32_16x16x32_bf16(a[tt], B[0][kt], acc[tt][0], 0, 0, 0);
                acc[tt][1] = __builtin_amdgcn_mfma_f32_16x16x32_bf16(a[tt], B[1][kt], acc[tt][1], 0, 0, 0);
            }
        }
        int crow0 = kgrp * 4;
#pragma unroll
        for (int tt = 0; tt < 4; ++tt) {
            int tile = t0 + tt;
            if (tile < ntile) {
                int r0 = tile * 16;
#pragma unroll
                for (int j = 0; j < 4; ++j) {
                    int row = r0 + crow0 + j;
                    float dv = dinv[row];
                    zb[(size_t)row * 128 + col0] = f2b((acc[tt][0][j] + cv0) * dv);
                    zb[(size_t)row * 128 + col1] = f2b((acc[tt][1][j] + cv1) * dv);
                }
            }
        }
    }
}

// ---------------- aggregate + relu + BN stats: TWO nodes per wave, interleaved ----------------
// Fixed 64-slot rows (8 uint4/row), ZROW pads -> no guards: 16 gathers + 2 edge loads in flight.
__global__ __launch_bounds__(256) void k_agg(const unsigned short* __restrict__ zb,
                                             const int* __restrict__ cnt16,
                                             const unsigned short* __restrict__ ew,
                                             const float* __restrict__ dinv,
                                             const float* __restrict__ bias,
                                             unsigned int* __restrict__ tb,
                                             float* __restrict__ stats64, int n) {
    int tid = threadIdx.x;
    int l = tid & 63;
    int pair = __builtin_amdgcn_readfirstlane(blockIdx.x * 4 + (tid >> 6));
    int nodeA = pair * 2, nodeB = nodeA + 1;
    const unsigned int* zl = (const unsigned int*)zb + l;
    float sA0 = 0.f, sA1 = 0.f, sB0 = 0.f, sB1 = 0.f;
    int cA = cnt16[nodeA << 4], cB = cnt16[nodeB << 4];
    int iters = max((cA + 8) >> 3, (cB + 8) >> 3);   // <= 8
    const uint4* epA = (const uint4*)(ew + (size_t)nodeA * 64);
    const uint4* epB = (const uint4*)(ew + (size_t)nodeB * 64);
    uint4 qA = epA[0], qB = epB[0];
    for (int it = 1; it <= iters; ++it) {
        unsigned int a0 = zl[(qA.x & 0xffffu) << 6];
        unsigned int a1 = zl[(qA.x >> 16) << 6];
        unsigned int a2 = zl[(qA.y & 0xffffu) << 6];
        unsigned int a3 = zl[(qA.y >> 16) << 6];
        unsigned int a4 = zl[(qA.z & 0xffffu) << 6];
        unsigned int a5 = zl[(qA.z >> 16) << 6];
        unsigned int a6 = zl[(qA.w & 0xffffu) << 6];
        unsigned int a7 = zl[(qA.w >> 16) << 6];
        unsigned int b0 = zl[(qB.x & 0xffffu) << 6];
        unsigned int b1 = zl[(qB.x >> 16) << 6];
        unsigned int b2 = zl[(qB.y & 0xffffu) << 6];
        unsigned int b3 = zl[(qB.y >> 16) << 6];
        unsigned int b4 = zl[(qB.z & 0xffffu) << 6];
        unsigned int b5 = zl[(qB.z >> 16) << 6];
        unsigned int b6 = zl[(qB.w & 0xffffu) << 6];
        unsigned int b7 = zl[(qB.w >> 16) << 6];
        qA = epA[it];  // slack-safe prefetch
        qB = epB[it];
        sA0 += b2f_lo(a0); sA1 += b2f_hi(a0);
        sA0 += b2f_lo(a1); sA1 += b2f_hi(a1);
        sA0 += b2f_lo(a2); sA1 += b2f_hi(a2);
        sA0 += b2f_lo(a3); sA1 += b2f_hi(a3);
        sA0 += b2f_lo(a4); sA1 += b2f_hi(a4);
        sA0 += b2f_lo(a5); sA1 += b2f_hi(a5);
        sA0 += b2f_lo(a6); sA1 += b2f_hi(a6);
        sA0 += b2f_lo(a7); sA1 += b2f_hi(a7);
        sB0 += b2f_lo(b0); sB1 += b2f_hi(b0);
        sB0 += b2f_lo(b1); sB1 += b2f_hi(b1);
        sB0 += b2f_lo(b2); sB1 += b2f_hi(b2);
        sB0 += b2f_lo(b3); sB1 += b2f_hi(b3);
        sB0 += b2f_lo(b4); sB1 += b2f_hi(b4);
        sB0 += b2f_lo(b5); sB1 += b2f_hi(b5);
        sB0 += b2f_lo(b6); sB1 += b2f_hi(b6);
        sB0 += b2f_lo(b7); sB1 += b2f_hi(b7);
    }
    float b0f = bias[2 * l], b1f = bias[2 * l + 1];
    float ddA = dinv[nodeA], ddB = dinv[nodeB];
    float aA0 = fmaxf(fmaf(sA0, ddA, b0f), 0.f);
    float aA1 = fmaxf(fmaf(sA1, ddA, b1f), 0.f);
    float aB0 = fmaxf(fmaf(sB0, ddB, b0f), 0.f);
    float aB1 = fmaxf(fmaf(sB1, ddB, b1f), 0.f);
    tb[((size_t)nodeA << 6) | l] = pack2(aA0, aA1);
    tb[((size_t)nodeB << 6) | l] = pack2(aB0, aB1);
    __shared__ float red[4][256];
    red[0][tid] = aA0 + aB0;
    red[1][tid] = aA1 + aB1;
    red[2][tid] = aA0 * aA0 + aB0 * aB0;
    red[3][tid] = aA1 * aA1 + aB1 * aB1;
    __syncthreads();
    int k = tid >> 6, li = tid & 63;
    float v = red[k][li] + red[k][64 + li] + red[k][128 + li] + red[k][192 + li];
    int f = 2 * li + (k & 1) + ((k >> 1) ? 128 : 0);
    atomicAdd(&stats64[(blockIdx.x & 63) * 256 + f], v);
}

// ---------------- fused BN finalize + shift-dots + B pre-scale ----------------
template <int MODE>
__global__ void k_bn_findots(const float* __restrict__ stats64,
                             const float* __restrict__ g, const float* __restrict__ be,
                             float invn, float* __restrict__ ss_out,
                             const float* __restrict__ Wn, float* __restrict__ cn,
                             const float* __restrict__ Wl, const float* __restrict__ base,
                             float* __restrict__ cl,
                             const unsigned short* __restrict__ bpn_src,
                             unsigned short* __restrict__ bpn_dst,
                             const unsigned short* __restrict__ bpl_src,
                             unsigned short* __restrict__ bpl_dst) {
    int tid = threadIdx.x;  // 256
    float a = 0.f;
#pragma unroll 8
    for (int c = 0; c < 64; ++c) a += stats64[c * 256 + tid];
    __shared__ float sums[256];
    __shared__ float sh[128];
    __shared__ float scs[128];
    sums[tid] = a;
    __syncthreads();
    if (tid < 128) {
        float m = sums[tid] * invn;
        float var = sums[128 + tid] * invn - m * m;
        float sc = g[tid] * rsqrtf(var + BN_EPS);
        scs[tid] = sc;
        sh[tid] = fmaf(-m, sc, be[tid]);
    }
    __syncthreads();
    if (blockIdx.x == 0 && tid < 128) {
        ss_out[tid] = scs[tid];
        ss_out[128 + tid] = sh[tid];
    }
    bool doCl = (MODE == 2) ? (blockIdx.x == 0) : (blockIdx.x == 1);
    bool doCn = (MODE < 2) && (blockIdx.x == 0);
    if (doCl || doCn) {
        const float* W = doCl ? Wl : Wn;
        int col = tid & 127, half = tid >> 7;
        float acc = 0.f;
#pragma unroll 4
        for (int k = half * 64; k < half * 64 + 64; ++k) acc = fmaf(sh[k], W[k * 128 + col], acc);
        __syncthreads();
        sums[tid] = acc;
        __syncthreads();
        if (tid < 128) {
            float tot = sums[tid] + sums[128 + tid];
            if (doCl) cl[tid] = ((MODE == 0) ? base[tid] : cl[tid]) + tot;
            else cn[tid] = tot;
        }
    }
    // scale prepacked B fragments by per-k scs
    int beg = blockIdx.x * 8192;
    if (MODE < 2) {
        for (int idx = beg + tid; idx < beg + 8192; idx += 256) {
            int k = ((idx >> 9) & 3) * 32 + ((idx >> 7) & 3) * 8 + (idx & 7);
            bpn_dst[idx] = f2b(us2f(bpn_src[idx]) * scs[k]);
        }
    }
    for (int idx = beg + tid; idx < beg + 8192; idx += 256) {
        int k = ((idx >> 9) & 3) * 32 + ((idx >> 7) & 3) * 8 + (idx & 7);
        bpl_dst[idx] = f2b(us2f(bpl_src[idx]) * scs[k]);
    }
}

// ---------------- final GEMM: out = relu([t1|t2|t3] @ BpL + cl), all-reg B, persistent ----------------
__global__ __launch_bounds__(256) void k_gemm_final(const unsigned short* __restrict__ t1,
                                                    const unsigned short* __restrict__ t2,
                                                    const unsigned short* __restrict__ t3,
                                                    const unsigned short* __restrict__ Bp,
                                                    const float* __restrict__ cl,
                                                    float* __restrict__ out, int n) {
    int tid = threadIdx.x;
    int l = tid & 63, w = tid >> 6;
    const short8* bp8 = (const short8*)Bp;
    short8 B[2][12];
#pragma unroll
    for (int b = 0; b < 3; ++b)
#pragma unroll
        for (int i = 0; i < 2; ++i)
#pragma unroll
            for (int kt = 0; kt < 4; ++kt)
                B[i][b * 4 + kt] = bp8[b * 2048 + ((2 * w + i) * 4 + kt) * 64 + l];
    int kgrp = l >> 4, rit = l & 15, ccol = l & 15;
    int ntile = n >> 4;
    int col0 = 2 * w * 16 + ccol, col1 = col0 + 16;
    float cv0 = cl[col0], cv1 = cl[col1];
    const unsigned short* tbs[3] = {t1, t2, t3};
    for (int t0 = blockIdx.x * 4; t0 < ntile; t0 += gridDim.x * 4) {
        f32x4 acc[4][2];
#pragma unroll
        for (int tt = 0; tt < 4; ++tt) { acc[tt][0] = (f32x4)(0.f); acc[tt][1] = (f32x4)(0.f); }
#pragma unroll
        for (int b = 0; b < 3; ++b) {
            const unsigned short* tp = tbs[b];
#pragma unroll
            for (int kt = 0; kt < 4; ++kt) {
                short8 a[4];
#pragma unroll
                for (int tt = 0; tt < 4; ++tt) {
                    int tile = min(t0 + tt, ntile - 1);
                    a[tt] = *(const short8*)(tp + (size_t)(tile * 16 + rit) * 128 + kgrp * 8 + kt * 32);
                }
#pragma unroll
                for (int tt = 0; tt < 4; ++tt) {
                    acc[tt][0] = __builtin_amdgcn_mfma_f32_16x16x32_bf16(a[tt], B[0][b * 4 + kt], acc[tt][0], 0, 0, 0);
                    acc[tt][1] = __builtin_amdgcn_mfma_f32_16x16x32_bf16(a[tt], B[1][b * 4 + kt], acc[tt][1], 0, 0, 0);
                }
            }
        }
        int crow0 = kgrp * 4;
#pragma unroll
        for (int tt = 0; tt < 4; ++tt) {
            int tile = t0 + tt;
            if (tile < ntile) {
                int r0 = tile * 16;
#pragma unroll
                for (int j = 0; j < 4; ++j) {
                    int row = r0 + crow0 + j;
                    out[(size_t)row * 128 + col0] = fmaxf(acc[tt][0][j] + cv0, 0.f);
                    out[(size_t)row * 128 + col1] = fmaxf(acc[tt][1][j] + cv1, 0.f);
                }
            }
        }
    }
}

extern "C" void kernel_launch(void* const* d_in, const int* in_sizes, int n_in,
                              void* d_out, int out_size, void* d_ws, size_t ws_size,
                              hipStream_t stream) {
    const float* x   = (const float*)d_in[0];
    const int*   ei  = (const int*)d_in[1];
    const float* W1  = (const float*)d_in[3];
    const float* b1  = (const float*)d_in[4];
    const float* g1  = (const float*)d_in[5];
    const float* be1 = (const float*)d_in[6];
    const float* W2  = (const float*)d_in[7];
    const float* b2  = (const float*)d_in[8];
    const float* g2  = (const float*)d_in[9];
    const float* be2 = (const float*)d_in[10];
    const float* W3  = (const float*)d_in[11];
    const float* b3  = (const float*)d_in[12];
    const float* g3  = (const float*)d_in[13];
    const float* be3 = (const float*)d_in[14];
    const float* Wl  = (const float*)d_in[15];
    const float* bl  = (const float*)d_in[16];
    float* out = (float*)d_out;

    const int n = N_NODES;
    const int E = in_sizes[1] / 2;

    char* ws = (char*)d_ws;
    size_t off = 0;
    auto alloc = [&](size_t bytes) -> void* {
        void* p = ws + off;
        off += (bytes + 255) & ~((size_t)255);
        return p;
    };
    // zero-region: strided cnt + 3 striped stats buffers, contiguous, one memset
    int*            cnt16    = (int*)alloc((size_t)n * 16 * 4);
    float*          st1      = (float*)alloc(64 * 256 * 4);
    float*          st2      = (float*)alloc(64 * 256 * 4);
    float*          st3      = (float*)alloc(64 * 256 * 4);
    size_t zero_bytes = (size_t)((char*)st3 + 64 * 256 * 4 - (char*)cnt16);

    float*          dinv     = (float*)alloc((size_t)n * 4);
    float*          ss1      = (float*)alloc(256 * 4);
    float*          ss2      = (float*)alloc(256 * 4);
    float*          ss3      = (float*)alloc(256 * 4);
    float*          c2       = (float*)alloc(128 * 4);
    float*          c3       = (float*)alloc(128 * 4);
    float*          cl       = (float*)alloc(128 * 4);
    unsigned short* ew       = (unsigned short*)alloc(((size_t)n * 64 + 1024) * 2);  // fixed 64 slots/node
    unsigned short* bp       = (unsigned short*)alloc(6 * 16384 * 2);   // raw prepack
    unsigned short* bpsN     = (unsigned short*)alloc(16384 * 2);       // scaled next-layer W
    unsigned short* bpsL     = (unsigned short*)alloc(3 * 16384 * 2);   // scaled Wl blocks
    unsigned short* zb       = (unsigned short*)alloc((size_t)(n + 1) * 128 * 2);  // +zero row
    unsigned int*   tb1      = (unsigned int*)alloc((size_t)n * 64 * 4);
    unsigned int*   tb2      = (unsigned int*)alloc((size_t)n * 64 * 4);
    unsigned int*   tb3      = (unsigned int*)alloc((size_t)n * 64 * 4);

    hipMemsetAsync(cnt16, 0, zero_bytes, stream);

    // ---- init: prepack + ew pattern-fill + zb zero row ----
    k_init<<<PREPBLK + EWINITBLK, 256, 0, stream>>>(W1, W2, W3, Wl, bp, (uint4*)ew,
                                                    (unsigned int*)zb, n);

    const unsigned short* t1u = (const unsigned short*)tb1;
    const unsigned short* t2u = (const unsigned short*)tb2;
    const unsigned short* t3u = (const unsigned short*)tb3;
    float invn = 1.0f / n;
    int aggblk = n / 8;   // two nodes per wave

    // ---- CSR-lite build: fill then dinv+self-loop ----
    k_fill<<<FILLBLK, 256, 0, stream>>>(ei, cnt16, ew, E);
    k_dinv_self<<<(n + 255) / 256, 256, 0, stream>>>(cnt16, dinv, ew, n);

    // ---- layer 1 (dinv-scaled epilogue; raw W1) ----
    k_gemm_z<0, 1><<<GEMMBLK, 256, 0, stream>>>(x, bp, nullptr, dinv, zb, n);
    k_agg<<<aggblk, 256, 0, stream>>>(zb, cnt16, ew, dinv, b1, tb1, st1, n);
    k_bn_findots<0><<<2, 256, 0, stream>>>(st1, g1, be1, invn, ss1, W2, c2, Wl, bl, cl,
                                           bp + 16384, bpsN, bp + 3 * 16384, bpsL);

    // ---- layer 2 (prescaled W2) ----
    k_gemm_z<1, 0><<<GEMMBLK, 256, 0, stream>>>(t1u, bpsN, c2, dinv, zb, n);
    k_agg<<<aggblk, 256, 0, stream>>>(zb, cnt16, ew, dinv, b2, tb2, st2, n);
    k_bn_findots<1><<<2, 256, 0, stream>>>(st2, g2, be2, invn, ss2, W3, c3, Wl + 16384, nullptr, cl,
                                           bp + 2 * 16384, bpsN, bp + 4 * 16384, bpsL + 16384);

    // ---- layer 3 (prescaled W3) ----
    k_gemm_z<1, 0><<<GEMMBLK, 256, 0, stream>>>(t2u, bpsN, c3, dinv, zb, n);
    k_agg<<<aggblk, 256, 0, stream>>>(zb, cnt16, ew, dinv, b3, tb3, st3, n);
    k_bn_findots<2><<<2, 256, 0, stream>>>(st3, g3, be3, invn, ss3, nullptr, nullptr,
                                           Wl + 2 * 16384, nullptr, cl,
                                           nullptr, nullptr, bp + 5 * 16384, bpsL + 2 * 16384);

    // ---- final fused GEMM over K=384 (prescaled Wl, all-reg B) ----
    k_gemm_final<<<GEMMBLK, 256, 0, stream>>>(t1u, t2u, t3u, bpsL, cl, out, n);
}

// Round 19
// 263.695 us; speedup vs baseline: 1.0421x; 1.0266x over previous
//
#include <hip/hip_runtime.h>

#define N_NODES 50000
#define BN_EPS 1e-5f
#define GEMMBLK 391
#define FILLBLK 512
#define PREPBLK 24
#define INITBLK 200
#define ZROW N_NODES

typedef __attribute__((ext_vector_type(8))) short short8;
typedef __attribute__((ext_vector_type(4))) float f32x4;

__device__ __forceinline__ unsigned short f2b(float x) {
    unsigned int u = __float_as_uint(x);
    unsigned int r = (u + 0x7fffu + ((u >> 16) & 1u)) >> 16;
    return (unsigned short)r;
}
__device__ __forceinline__ float b2f_lo(unsigned int u) { return __uint_as_float(u << 16); }
__device__ __forceinline__ float b2f_hi(unsigned int u) { return __uint_as_float(u & 0xffff0000u); }
__device__ __forceinline__ unsigned int pack2(float lo, float hi) {
    return (unsigned int)f2b(lo) | ((unsigned int)f2b(hi) << 16);
}
__device__ __forceinline__ float us2f(unsigned short s) {
    return __uint_as_float(((unsigned int)s) << 16);
}

// per-block int64 detection: odd 32-bit words of first 256 edge entries all zero <=> int64
__device__ __forceinline__ int detect_is64(const int* __restrict__ e, int tid) {
    __shared__ int snz[4];
    int lane = tid & 63, wv = tid >> 6;
    int v = e[2 * tid + 1];
    unsigned long long b = __ballot(v != 0);
    if (lane == 0) snz[wv] = (b != 0ULL) ? 1 : 0;
    __syncthreads();
    return !(snz[0] | snz[1] | snz[2] | snz[3]);
}

__device__ __forceinline__ int edge_at(const int* e32, const long long* e64, int is64, long long idx) {
    return is64 ? (int)e64[idx] : e32[idx];
}

// ---------------- init: W prepack + ew <- ZROW pattern + zero cnt/stats + zb zero row ----------------
__global__ void k_init(const float* __restrict__ W1, const float* __restrict__ W2,
                       const float* __restrict__ W3, const float* __restrict__ Wl,
                       unsigned short* __restrict__ bp, uint4* __restrict__ ew4,
                       uint4* __restrict__ zero4, int nzero4,
                       unsigned int* __restrict__ zb32, int n) {
    if (blockIdx.x < PREPBLK) {
        int job = blockIdx.x >> 2, q = blockIdx.x & 3;
        const float* src;
        int rowoff = 0;
        if (job == 0) src = W1;
        else if (job == 1) src = W2;
        else if (job == 2) src = W3;
        else { src = Wl; rowoff = (job - 3) * 128; }
        unsigned short* dst = bp + job * 16384;
        for (int idx = q * 4096 + threadIdx.x; idx < q * 4096 + 4096; idx += 256) {
            int j = idx & 7, l = (idx >> 3) & 63, kt = (idx >> 9) & 3, nt = idx >> 11;
            int row = kt * 32 + (l >> 4) * 8 + j;
            int col = nt * 16 + (l & 15);
            dst[idx] = f2b(src[(rowoff + row) * 128 + col]);
        }
        return;
    }
    int b = blockIdx.x - PREPBLK;
    if (b == 0 && threadIdx.x < 64)
        zb32[(size_t)n * 64 + threadIdx.x] = 0;   // ZROW zero row (128 bf16)
    // zero region: cnt16 + stats (nzero4 uint4s)
    uint4 zz4 = make_uint4(0, 0, 0, 0);
    for (int i = b * 256 + threadIdx.x; i < nzero4; i += INITBLK * 256)
        zero4[i] = zz4;
    // ew init: n*64 u16 = n*8 uint4, pattern ZROW in every u16
    unsigned int zz = ((unsigned int)ZROW << 16) | (unsigned int)ZROW;
    uint4 z = make_uint4(zz, zz, zz, zz);
    int total = n * 8;
    for (int i = b * 256 + threadIdx.x; i < total; i += INITBLK * 256)
        ew4[i] = z;
}

// ---------------- fill: fixed-64-slot scatter, 8-deep pipelined atomics ----------------
__global__ __launch_bounds__(256) void k_fill(const int* __restrict__ e,
                                              int* __restrict__ cnt16,
                                              unsigned short* __restrict__ ew, int E) {
    int is64 = detect_is64(e, threadIdx.x);
    const long long* e64 = (const long long*)e;
    int T = FILLBLK * 256;
    for (int base = blockIdx.x * 256 + threadIdx.x; base < E; base += T * 8) {
        int d[8], s[8], pos[8];
        bool vld[8];
#pragma unroll
        for (int j = 0; j < 8; ++j) {
            int idx = base + j * T;
            vld[j] = idx < E;
            int ci = vld[j] ? idx : 0;
            d[j] = edge_at(e, e64, is64, (long long)E + ci);
            s[j] = edge_at(e, e64, is64, ci);
        }
#pragma unroll
        for (int j = 0; j < 8; ++j)
            pos[j] = vld[j] ? atomicAdd(&cnt16[d[j] << 4], 1) : 64;
#pragma unroll
        for (int j = 0; j < 8; ++j)
            if (vld[j] && pos[j] < 64) ew[d[j] * 64 + pos[j]] = (unsigned short)s[j];
    }
}

// ---------------- layer GEMM: zb = rsqrt(c+1) .* (A @ Bp [+ c]), bf16 out, persistent ----------------
template <int HAS_C, int A32>
__global__ __launch_bounds__(256) void k_gemm_z(const void* __restrict__ Av,
                                                const unsigned short* __restrict__ Bp,
                                                const float* __restrict__ cvec,
                                                const int* __restrict__ cnt16,
                                                unsigned short* __restrict__ zb, int n) {
    int tid = threadIdx.x;
    int l = tid & 63, w = tid >> 6;
    const short8* bp8 = (const short8*)Bp;
    short8 B[2][4];
#pragma unroll
    for (int i = 0; i < 2; ++i)
#pragma unroll
        for (int kt = 0; kt < 4; ++kt)
            B[i][kt] = bp8[((2 * w + i) * 4 + kt) * 64 + l];
    int kgrp = l >> 4, rit = l & 15, ccol = l & 15;
    int ntile = n >> 4;
    int col0 = 2 * w * 16 + ccol, col1 = col0 + 16;
    float cv0 = HAS_C ? cvec[col0] : 0.f;
    float cv1 = HAS_C ? cvec[col1] : 0.f;
    for (int t0 = blockIdx.x * 4; t0 < ntile; t0 += gridDim.x * 4) {
        f32x4 acc[4][2];
#pragma unroll
        for (int tt = 0; tt < 4; ++tt) { acc[tt][0] = (f32x4)(0.f); acc[tt][1] = (f32x4)(0.f); }
#pragma unroll
        for (int kt = 0; kt < 4; ++kt) {
            short8 a[4];
#pragma unroll
            for (int tt = 0; tt < 4; ++tt) {
                int tile = min(t0 + tt, ntile - 1);
                size_t base = (size_t)(tile * 16 + rit) * 128 + kgrp * 8 + kt * 32;
                if (A32) {
                    const float* a32 = (const float*)Av + base;
                    float4 fa = *(const float4*)a32;
                    float4 fb = *(const float4*)(a32 + 4);
                    short8 af;
                    af[0] = (short)f2b(fa.x); af[1] = (short)f2b(fa.y);
                    af[2] = (short)f2b(fa.z); af[3] = (short)f2b(fa.w);
                    af[4] = (short)f2b(fb.x); af[5] = (short)f2b(fb.y);
                    af[6] = (short)f2b(fb.z); af[7] = (short)f2b(fb.w);
                    a[tt] = af;
                } else {
                    a[tt] = *(const short8*)((const unsigned short*)Av + base);
                }
            }
#pragma unroll
            for (int tt = 0; tt < 4; ++tt) {
                acc[tt][0] = __builtin_amdgcn_mfma_f32_16x16x32_bf16(a[tt], B[0][kt], acc[tt][0], 0, 0, 0);
                acc[tt][1] = __builtin_amdgcn_mfma_f32_16x16x32_bf16(a[tt], B[1][kt], acc[tt][1], 0, 0, 0);
            }
        }
        int crow0 = kgrp * 4;
#pragma unroll
        for (int tt = 0; tt < 4; ++tt) {
            int tile = t0 + tt;
            if (tile < ntile) {
                int r0 = tile * 16;
#pragma unroll
                for (int j = 0; j < 4; ++j) {
                    int row = r0 + crow0 + j;
                    float dv = rsqrtf((float)(cnt16[row << 4] + 1));
                    zb[(size_t)row * 128 + col0] = f2b((acc[tt][0][j] + cv0) * dv);
                    zb[(size_t)row * 128 + col1] = f2b((acc[tt][1][j] + cv1) * dv);
                }
            }
        }
    }
}

// ---------------- aggregate + relu + BN stats: TWO nodes per wave, interleaved ----------------
// Fixed 64-slot rows (8 uint4/row); slots [c,64) are ZROW pads; self-loop added explicitly.
__global__ __launch_bounds__(256) void k_agg(const unsigned short* __restrict__ zb,
                                             const int* __restrict__ cnt16,
                                             const unsigned short* __restrict__ ew,
                                             const float* __restrict__ bias,
                                             unsigned int* __restrict__ tb,
                                             float* __restrict__ stats64, int n) {
    int tid = threadIdx.x;
    int l = tid & 63;
    int pair = __builtin_amdgcn_readfirstlane(blockIdx.x * 4 + (tid >> 6));
    int nodeA = pair * 2, nodeB = nodeA + 1;
    const unsigned int* zl = (const unsigned int*)zb + l;
    // self-loop terms (zb rows already rsqrt-scaled)
    unsigned int usA = zl[(unsigned int)nodeA << 6];
    unsigned int usB = zl[(unsigned int)nodeB << 6];
    float sA0 = b2f_lo(usA), sA1 = b2f_hi(usA);
    float sB0 = b2f_lo(usB), sB1 = b2f_hi(usB);
    int cA = min(cnt16[nodeA << 4], 64), cB = min(cnt16[nodeB << 4], 64);
    int iters = max((cA + 7) >> 3, (cB + 7) >> 3);   // <= 8
    const uint4* epA = (const uint4*)(ew + (size_t)nodeA * 64);
    const uint4* epB = (const uint4*)(ew + (size_t)nodeB * 64);
    uint4 qA = epA[0], qB = epB[0];
    for (int it = 1; it <= iters; ++it) {
        unsigned int a0 = zl[(qA.x & 0xffffu) << 6];
        unsigned int a1 = zl[(qA.x >> 16) << 6];
        unsigned int a2 = zl[(qA.y & 0xffffu) << 6];
        unsigned int a3 = zl[(qA.y >> 16) << 6];
        unsigned int a4 = zl[(qA.z & 0xffffu) << 6];
        unsigned int a5 = zl[(qA.z >> 16) << 6];
        unsigned int a6 = zl[(qA.w & 0xffffu) << 6];
        unsigned int a7 = zl[(qA.w >> 16) << 6];
        unsigned int b0 = zl[(qB.x & 0xffffu) << 6];
        unsigned int b1 = zl[(qB.x >> 16) << 6];
        unsigned int b2 = zl[(qB.y & 0xffffu) << 6];
        unsigned int b3 = zl[(qB.y >> 16) << 6];
        unsigned int b4 = zl[(qB.z & 0xffffu) << 6];
        unsigned int b5 = zl[(qB.z >> 16) << 6];
        unsigned int b6 = zl[(qB.w & 0xffffu) << 6];
        unsigned int b7 = zl[(qB.w >> 16) << 6];
        qA = epA[it];  // slack-safe prefetch
        qB = epB[it];
        sA0 += b2f_lo(a0); sA1 += b2f_hi(a0);
        sA0 += b2f_lo(a1); sA1 += b2f_hi(a1);
        sA0 += b2f_lo(a2); sA1 += b2f_hi(a2);
        sA0 += b2f_lo(a3); sA1 += b2f_hi(a3);
        sA0 += b2f_lo(a4); sA1 += b2f_hi(a4);
        sA0 += b2f_lo(a5); sA1 += b2f_hi(a5);
        sA0 += b2f_lo(a6); sA1 += b2f_hi(a6);
        sA0 += b2f_lo(a7); sA1 += b2f_hi(a7);
        sB0 += b2f_lo(b0); sB1 += b2f_hi(b0);
        sB0 += b2f_lo(b1); sB1 += b2f_hi(b1);
        sB0 += b2f_lo(b2); sB1 += b2f_hi(b2);
        sB0 += b2f_lo(b3); sB1 += b2f_hi(b3);
        sB0 += b2f_lo(b4); sB1 += b2f_hi(b4);
        sB0 += b2f_lo(b5); sB1 += b2f_hi(b5);
        sB0 += b2f_lo(b6); sB1 += b2f_hi(b6);
        sB0 += b2f_lo(b7); sB1 += b2f_hi(b7);
    }
    float b0f = bias[2 * l], b1f = bias[2 * l + 1];
    float ddA = rsqrtf((float)(cA + 1)), ddB = rsqrtf((float)(cB + 1));
    float aA0 = fmaxf(fmaf(sA0, ddA, b0f), 0.f);
    float aA1 = fmaxf(fmaf(sA1, ddA, b1f), 0.f);
    float aB0 = fmaxf(fmaf(sB0, ddB, b0f), 0.f);
    float aB1 = fmaxf(fmaf(sB1, ddB, b1f), 0.f);
    tb[((size_t)nodeA << 6) | l] = pack2(aA0, aA1);
    tb[((size_t)nodeB << 6) | l] = pack2(aB0, aB1);
    __shared__ float red[4][256];
    red[0][tid] = aA0 + aB0;
    red[1][tid] = aA1 + aB1;
    red[2][tid] = aA0 * aA0 + aB0 * aB0;
    red[3][tid] = aA1 * aA1 + aB1 * aB1;
    __syncthreads();
    int k = tid >> 6, li = tid & 63;
    float v = red[k][li] + red[k][64 + li] + red[k][128 + li] + red[k][192 + li];
    int f = 2 * li + (k & 1) + ((k >> 1) ? 128 : 0);
    atomicAdd(&stats64[(blockIdx.x & 63) * 256 + f], v);
}

// ---------------- fused BN finalize + shift-dots + B pre-scale ----------------
template <int MODE>
__global__ void k_bn_findots(const float* __restrict__ stats64,
                             const float* __restrict__ g, const float* __restrict__ be,
                             float invn, float* __restrict__ ss_out,
                             const float* __restrict__ Wn, float* __restrict__ cn,
                             const float* __restrict__ Wl, const float* __restrict__ base,
                             float* __restrict__ cl,
                             const unsigned short* __restrict__ bpn_src,
                             unsigned short* __restrict__ bpn_dst,
                             const unsigned short* __restrict__ bpl_src,
                             unsigned short* __restrict__ bpl_dst) {
    int tid = threadIdx.x;  // 256
    float a = 0.f;
#pragma unroll 8
    for (int c = 0; c < 64; ++c) a += stats64[c * 256 + tid];
    __shared__ float sums[256];
    __shared__ float sh[128];
    __shared__ float scs[128];
    sums[tid] = a;
    __syncthreads();
    if (tid < 128) {
        float m = sums[tid] * invn;
        float var = sums[128 + tid] * invn - m * m;
        float sc = g[tid] * rsqrtf(var + BN_EPS);
        scs[tid] = sc;
        sh[tid] = fmaf(-m, sc, be[tid]);
    }
    __syncthreads();
    if (blockIdx.x == 0 && tid < 128) {
        ss_out[tid] = scs[tid];
        ss_out[128 + tid] = sh[tid];
    }
    bool doCl = (MODE == 2) ? (blockIdx.x == 0) : (blockIdx.x == 1);
    bool doCn = (MODE < 2) && (blockIdx.x == 0);
    if (doCl || doCn) {
        const float* W = doCl ? Wl : Wn;
        int col = tid & 127, half = tid >> 7;
        float acc = 0.f;
#pragma unroll 4
        for (int k = half * 64; k < half * 64 + 64; ++k) acc = fmaf(sh[k], W[k * 128 + col], acc);
        __syncthreads();
        sums[tid] = acc;
        __syncthreads();
        if (tid < 128) {
            float tot = sums[tid] + sums[128 + tid];
            if (doCl) cl[tid] = ((MODE == 0) ? base[tid] : cl[tid]) + tot;
            else cn[tid] = tot;
        }
    }
    // scale prepacked B fragments by per-k scs
    int beg = blockIdx.x * 8192;
    if (MODE < 2) {
        for (int idx = beg + tid; idx < beg + 8192; idx += 256) {
            int k = ((idx >> 9) & 3) * 32 + ((idx >> 7) & 3) * 8 + (idx & 7);
            bpn_dst[idx] = f2b(us2f(bpn_src[idx]) * scs[k]);
        }
    }
    for (int idx = beg + tid; idx < beg + 8192; idx += 256) {
        int k = ((idx >> 9) & 3) * 32 + ((idx >> 7) & 3) * 8 + (idx & 7);
        bpl_dst[idx] = f2b(us2f(bpl_src[idx]) * scs[k]);
    }
}

// ---------------- final GEMM: out = relu([t1|t2|t3] @ BpL + cl), all-reg B, persistent ----------------
__global__ __launch_bounds__(256) void k_gemm_final(const unsigned short* __restrict__ t1,
                                                    const unsigned short* __restrict__ t2,
                                                    const unsigned short* __restrict__ t3,
                                                    const unsigned short* __restrict__ Bp,
                                                    const float* __restrict__ cl,
                                                    float* __restrict__ out, int n) {
    int tid = threadIdx.x;
    int l = tid & 63, w = tid >> 6;
    const short8* bp8 = (const short8*)Bp;
    short8 B[2][12];
#pragma unroll
    for (int b = 0; b < 3; ++b)
#pragma unroll
        for (int i = 0; i < 2; ++i)
#pragma unroll
            for (int kt = 0; kt < 4; ++kt)
                B[i][b * 4 + kt] = bp8[b * 2048 + ((2 * w + i) * 4 + kt) * 64 + l];
    int kgrp = l >> 4, rit = l & 15, ccol = l & 15;
    int ntile = n >> 4;
    int col0 = 2 * w * 16 + ccol, col1 = col0 + 16;
    float cv0 = cl[col0], cv1 = cl[col1];
    const unsigned short* tbs[3] = {t1, t2, t3};
    for (int t0 = blockIdx.x * 4; t0 < ntile; t0 += gridDim.x * 4) {
        f32x4 acc[4][2];
#pragma unroll
        for (int tt = 0; tt < 4; ++tt) { acc[tt][0] = (f32x4)(0.f); acc[tt][1] = (f32x4)(0.f); }
#pragma unroll
        for (int b = 0; b < 3; ++b) {
            const unsigned short* tp = tbs[b];
#pragma unroll
            for (int kt = 0; kt < 4; ++kt) {
                short8 a[4];
#pragma unroll
                for (int tt = 0; tt < 4; ++tt) {
                    int tile = min(t0 + tt, ntile - 1);
                    a[tt] = *(const short8*)(tp + (size_t)(tile * 16 + rit) * 128 + kgrp * 8 + kt * 32);
                }
#pragma unroll
                for (int tt = 0; tt < 4; ++tt) {
                    acc[tt][0] = __builtin_amdgcn_mfma_f32_16x16x32_bf16(a[tt], B[0][b * 4 + kt], acc[tt][0], 0, 0, 0);
                    acc[tt][1] = __builtin_amdgcn_mfma_f32_16x16x32_bf16(a[tt], B[1][b * 4 + kt], acc[tt][1], 0, 0, 0);
                }
            }
        }
        int crow0 = kgrp * 4;
#pragma unroll
        for (int tt = 0; tt < 4; ++tt) {
            int tile = t0 + tt;
            if (tile < ntile) {
                int r0 = tile * 16;
#pragma unroll
                for (int j = 0; j < 4; ++j) {
                    int row = r0 + crow0 + j;
                    out[(size_t)row * 128 + col0] = fmaxf(acc[tt][0][j] + cv0, 0.f);
                    out[(size_t)row * 128 + col1] = fmaxf(acc[tt][1][j] + cv1, 0.f);
                }
            }
        }
    }
}

extern "C" void kernel_launch(void* const* d_in, const int* in_sizes, int n_in,
                              void* d_out, int out_size, void* d_ws, size_t ws_size,
                              hipStream_t stream) {
    const float* x   = (const float*)d_in[0];
    const int*   ei  = (const int*)d_in[1];
    const float* W1  = (const float*)d_in[3];
    const float* b1  = (const float*)d_in[4];
    const float* g1  = (const float*)d_in[5];
    const float* be1 = (const float*)d_in[6];
    const float* W2  = (const float*)d_in[7];
    const float* b2  = (const float*)d_in[8];
    const float* g2  = (const float*)d_in[9];
    const float* be2 = (const float*)d_in[10];
    const float* W3  = (const float*)d_in[11];
    const float* b3  = (const float*)d_in[12];
    const float* g3  = (const float*)d_in[13];
    const float* be3 = (const float*)d_in[14];
    const float* Wl  = (const float*)d_in[15];
    const float* bl  = (const float*)d_in[16];
    float* out = (float*)d_out;

    const int n = N_NODES;
    const int E = in_sizes[1] / 2;

    char* ws = (char*)d_ws;
    size_t off = 0;
    auto alloc = [&](size_t bytes) -> void* {
        void* p = ws + off;
        off += (bytes + 255) & ~((size_t)255);
        return p;
    };
    // zero-region: strided cnt + 3 striped stats buffers, contiguous, zeroed in k_init
    int*            cnt16    = (int*)alloc((size_t)n * 16 * 4);
    float*          st1      = (float*)alloc(64 * 256 * 4);
    float*          st2      = (float*)alloc(64 * 256 * 4);
    float*          st3      = (float*)alloc(64 * 256 * 4);
    size_t zero_bytes = (size_t)((char*)st3 + 64 * 256 * 4 - (char*)cnt16);
    int nzero4 = (int)(zero_bytes / 16);

    float*          ss1      = (float*)alloc(256 * 4);
    float*          ss2      = (float*)alloc(256 * 4);
    float*          ss3      = (float*)alloc(256 * 4);
    float*          c2       = (float*)alloc(128 * 4);
    float*          c3       = (float*)alloc(128 * 4);
    float*          cl       = (float*)alloc(128 * 4);
    unsigned short* ew       = (unsigned short*)alloc(((size_t)n * 64 + 1024) * 2);  // fixed 64 slots/node
    unsigned short* bp       = (unsigned short*)alloc(6 * 16384 * 2);   // raw prepack
    unsigned short* bpsN     = (unsigned short*)alloc(16384 * 2);       // scaled next-layer W
    unsigned short* bpsL     = (unsigned short*)alloc(3 * 16384 * 2);   // scaled Wl blocks
    unsigned short* zb       = (unsigned short*)alloc((size_t)(n + 1) * 128 * 2);  // +zero row
    unsigned int*   tb1      = (unsigned int*)alloc((size_t)n * 64 * 4);
    unsigned int*   tb2      = (unsigned int*)alloc((size_t)n * 64 * 4);
    unsigned int*   tb3      = (unsigned int*)alloc((size_t)n * 64 * 4);

    // ---- init: prepack + zero cnt/stats + ew pattern + zb zero row (no memset) ----
    k_init<<<PREPBLK + INITBLK, 256, 0, stream>>>(W1, W2, W3, Wl, bp, (uint4*)ew,
                                                  (uint4*)cnt16, nzero4,
                                                  (unsigned int*)zb, n);

    const unsigned short* t1u = (const unsigned short*)tb1;
    const unsigned short* t2u = (const unsigned short*)tb2;
    const unsigned short* t3u = (const unsigned short*)tb3;
    float invn = 1.0f / n;
    int aggblk = n / 8;   // two nodes per wave

    // ---- fill (positions from atomic counters; no scan, no dinv pass) ----
    k_fill<<<FILLBLK, 256, 0, stream>>>(ei, cnt16, ew, E);

    // ---- layer 1 (rsqrt epilogue from cnt16; raw W1) ----
    k_gemm_z<0, 1><<<GEMMBLK, 256, 0, stream>>>(x, bp, nullptr, cnt16, zb, n);
    k_agg<<<aggblk, 256, 0, stream>>>(zb, cnt16, ew, b1, tb1, st1, n);
    k_bn_findots<0><<<2, 256, 0, stream>>>(st1, g1, be1, invn, ss1, W2, c2, Wl, bl, cl,
                                           bp + 16384, bpsN, bp + 3 * 16384, bpsL);

    // ---- layer 2 (prescaled W2) ----
    k_gemm_z<1, 0><<<GEMMBLK, 256, 0, stream>>>(t1u, bpsN, c2, cnt16, zb, n);
    k_agg<<<aggblk, 256, 0, stream>>>(zb, cnt16, ew, b2, tb2, st2, n);
    k_bn_findots<1><<<2, 256, 0, stream>>>(st2, g2, be2, invn, ss2, W3, c3, Wl + 16384, nullptr, cl,
                                           bp + 2 * 16384, bpsN, bp + 4 * 16384, bpsL + 16384);

    // ---- layer 3 (prescaled W3) ----
    k_gemm_z<1, 0><<<GEMMBLK, 256, 0, stream>>>(t2u, bpsN, c3, cnt16, zb, n);
    k_agg<<<aggblk, 256, 0, stream>>>(zb, cnt16, ew, b3, tb3, st3, n);
    k_bn_findots<2><<<2, 256, 0, stream>>>(st3, g3, be3, invn, ss3, nullptr, nullptr,
                                           Wl + 2 * 16384, nullptr, cl,
                                           nullptr, nullptr, bp + 5 * 16384, bpsL + 2 * 16384);

    // ---- final fused GEMM over K=384 (prescaled Wl, all-reg B) ----
    k_gemm_final<<<GEMMBLK, 256, 0, stream>>>(t1u, t2u, t3u, bpsL, cl, out, n);
}